// Round 14
// baseline (66.954 us; speedup 1.0000x reference)
//
#include <hip/hip_runtime.h>

#define N_NODES 100000
#define N_EDGES 320000
#define Q 4096
#define HID 128
#define DIN 256
#define NSLOT (3 * Q)   // 12288
#define CAP 32
#define QPB 16
#define MAXACT 96       // max active edges per 256-edge block (mean ~30, +13 sigma)

// ---------------- K1: slot = -1, cnt = 0 ----------------
__global__ __launch_bounds__(256) void k_init(int4* __restrict__ slot4,
                                              int4* __restrict__ cnt4) {
    int i = blockIdx.x * 256 + threadIdx.x;
    if (i < N_NODES / 4) slot4[i] = make_int4(-1, -1, -1, -1);
    else if (i < N_NODES / 4 + NSLOT / 4) cnt4[i - N_NODES / 4] = make_int4(0, 0, 0, 0);
}

// ---------------- K2: claim slots via CAS ----------------
__global__ __launch_bounds__(256) void k_claim(const int* __restrict__ s_idx,
                                               const int* __restrict__ p_idx,
                                               const int* __restrict__ n_idx,
                                               int* __restrict__ slot) {
    int i = blockIdx.x * 256 + threadIdx.x;   // 0 .. NSLOT-1
    int t = i >> 12;
    int q = i & (Q - 1);
    int node = (t == 0 ? s_idx : (t == 1 ? p_idx : n_idx))[q];
    atomicCAS(&slot[node], -1, i);
}

// ---------------- K3: build + staged ef copy ----------------
// 1250 blocks x 256 threads; block scans 256 contiguous edges, then the
// 4 waves cooperatively copy active ef rows into efbuf (streamed reads).
__global__ __launch_bounds__(256) void k_build(
    const int* __restrict__ src, const int* __restrict__ dst,
    const float* __restrict__ bt, const float* __restrict__ node_ts,
    const float* __restrict__ ef,
    const int* __restrict__ slot, int* __restrict__ cnt,
    float* __restrict__ efbuf, float* __restrict__ tdbuf) {
    __shared__ int   s_row[MAXACT];   // sl*CAP+pos
    __shared__ int   s_e[MAXACT];
    __shared__ float s_td[MAXACT];
    __shared__ int   lcnt;
    const int tid  = threadIdx.x;
    const int base = blockIdx.x * 256;

    if (tid == 0) lcnt = 0;
    __syncthreads();

    {
        int e  = base + tid;
        int sl = slot[dst[e]];
        if (sl >= 0) {
            int pos = atomicAdd(&cnt[sl], 1);
            if (pos < CAP) {
                int w = atomicAdd(&lcnt, 1);
                if (w < MAXACT) {
                    s_row[w] = sl * CAP + pos;
                    s_e[w]   = e;
                    s_td[w]  = bt[e] - node_ts[src[e]];
                }
            }
        }
    }
    __syncthreads();

    const int m    = lcnt < MAXACT ? lcnt : MAXACT;
    const int wv   = tid >> 6;
    const int lane = tid & 63;
    for (int r = wv; r < m; r += 4) {
        int   row = s_row[r];
        int   e   = s_e[r];
        float2 v  = *reinterpret_cast<const float2*>(ef + (size_t)e * 128 + 2 * lane);
        *reinterpret_cast<float2*>(efbuf + (size_t)row * 128 + 2 * lane) = v;
        if (lane == 0) tdbuf[row] = s_td[r];
    }
}

// ---------------- K4: aggregate h rows (streamed efbuf reads) ----------
// 3072 blocks x 256 threads = 12288 waves; lane-parallel over 4 edge slots.
__global__ __launch_bounds__(256) void k_aggregate(
    const int* __restrict__ cnt, const float* __restrict__ efbuf,
    const float* __restrict__ tdbuf,
    const float* __restrict__ time_w, const float* __restrict__ time_b,
    float* __restrict__ h) {
    const int s    = (blockIdx.x * 256 + threadIdx.x) >> 6;  // slot 0..12287
    const int lane = threadIdx.x & 63;
    const int j    = lane >> 4;       // edge slot 0..3
    const int g    = lane & 15;       // col group 0..15
    const float4 tw0 = *reinterpret_cast<const float4*>(time_w + 8 * g);
    const float4 tw1 = *reinterpret_cast<const float4*>(time_w + 8 * g + 4);
    const float4 tb0 = *reinterpret_cast<const float4*>(time_b + 8 * g);
    const float4 tb1 = *reinterpret_cast<const float4*>(time_b + 8 * g + 4);

    int n = cnt[s]; if (n > CAP) n = CAP;
    float4 accA = {0.f, 0.f, 0.f, 0.f}, accB = {0.f, 0.f, 0.f, 0.f};
    float4 tcA  = {0.f, 0.f, 0.f, 0.f}, tcB  = {0.f, 0.f, 0.f, 0.f};
    for (int jb = j; jb < n; jb += 4) {
        const float* rp = efbuf + ((size_t)s * CAP + jb) * 128;
        float4 vA = *reinterpret_cast<const float4*>(rp + 4 * g);
        float4 vB = *reinterpret_cast<const float4*>(rp + 64 + 4 * g);
        float td = tdbuf[(size_t)s * CAP + jb];
        accA.x += vA.x; accA.y += vA.y; accA.z += vA.z; accA.w += vA.w;
        accB.x += vB.x; accB.y += vB.y; accB.z += vB.z; accB.w += vB.w;
        tcA.x += __cosf(td * tw0.x + tb0.x);
        tcA.y += __cosf(td * tw0.y + tb0.y);
        tcA.z += __cosf(td * tw0.z + tb0.z);
        tcA.w += __cosf(td * tw0.w + tb0.w);
        tcB.x += __cosf(td * tw1.x + tb1.x);
        tcB.y += __cosf(td * tw1.y + tb1.y);
        tcB.z += __cosf(td * tw1.z + tb1.z);
        tcB.w += __cosf(td * tw1.w + tb1.w);
    }
#define RED2(v) { v += __shfl_xor(v, 16); v += __shfl_xor(v, 32); }
    RED2(accA.x) RED2(accA.y) RED2(accA.z) RED2(accA.w)
    RED2(accB.x) RED2(accB.y) RED2(accB.z) RED2(accB.w)
    RED2(tcA.x)  RED2(tcA.y)  RED2(tcA.z)  RED2(tcA.w)
    RED2(tcB.x)  RED2(tcB.y)  RED2(tcB.z)  RED2(tcB.w)
#undef RED2
    if (j == 0) {
        float* hp = h + (size_t)s * DIN;
        *reinterpret_cast<float4*>(hp + 4 * g)       = accA;
        *reinterpret_cast<float4*>(hp + 64 + 4 * g)  = accB;
        *reinterpret_cast<float4*>(hp + 128 + 8 * g) = tcA;
        *reinterpret_cast<float4*>(hp + 132 + 8 * g) = tcB;
    }
}

// ---------------- K5: predictor (proven, QPB=16, 256 blocks) -----------
__global__ __launch_bounds__(256) void k_predictor(
    const int* __restrict__ s_idx, const int* __restrict__ p_idx,
    const int* __restrict__ n_idx, const int* __restrict__ slot,
    const float* __restrict__ h,
    const float* __restrict__ W_src, const float* __restrict__ b_src,
    const float* __restrict__ W_dst, const float* __restrict__ b_dst,
    const float* __restrict__ W_out, const float* __restrict__ b_out,
    float* __restrict__ out) {
    __shared__ float emb[QPB * 3][DIN];       // 48 KB; row = t*16 + q
    const int tid   = threadIdx.x;
    const int qbase = blockIdx.x * QPB;

    for (int r = tid; r < QPB * 3 * 64; r += 256) {
        int row = r >> 6;                     // 0..47
        int c4  = r & 63;
        int t   = row >> 4;
        int q   = row & 15;
        const int* idxarr = (t == 0) ? s_idx : (t == 1) ? p_idx : n_idx;
        int node = idxarr[qbase + q];
        int sl   = slot[node];
        float4 v = *reinterpret_cast<const float4*>(h + (size_t)sl * DIN + c4 * 4);
        *reinterpret_cast<float4*>(&emb[row][c4 * 4]) = v;
    }
    __syncthreads();

    const int cg  = tid & 31;
    const int j4  = cg << 2;
    const int grp = tid >> 5;
    const int q0  = grp * 2, q1 = grp * 2 + 1;

    float aS[2][4], aP[2][4], aN[2][4];
    #pragma unroll
    for (int c = 0; c < 4; ++c) {
        float bs = b_src[j4 + c], bd = b_dst[j4 + c];
        aS[0][c] = bs; aS[1][c] = bs;
        aP[0][c] = bd; aP[1][c] = bd;
        aN[0][c] = bd; aN[1][c] = bd;
    }

    const float* e_s0 = emb[0 * QPB + q0];
    const float* e_s1 = emb[0 * QPB + q1];
    const float* e_p0 = emb[1 * QPB + q0];
    const float* e_p1 = emb[1 * QPB + q1];
    const float* e_n0 = emb[2 * QPB + q0];
    const float* e_n1 = emb[2 * QPB + q1];
    const float* wsp = W_src + j4;
    const float* wdp = W_dst + j4;

    #pragma unroll 2
    for (int k = 0; k < DIN; k += 4) {
        float4 s0 = *reinterpret_cast<const float4*>(e_s0 + k);
        float4 s1 = *reinterpret_cast<const float4*>(e_s1 + k);
        float4 p0 = *reinterpret_cast<const float4*>(e_p0 + k);
        float4 p1 = *reinterpret_cast<const float4*>(e_p1 + k);
        float4 n0 = *reinterpret_cast<const float4*>(e_n0 + k);
        float4 n1 = *reinterpret_cast<const float4*>(e_n1 + k);
        #pragma unroll
        for (int kk = 0; kk < 4; ++kk) {
            float4 ws = *reinterpret_cast<const float4*>(wsp + (size_t)(k + kk) * HID);
            float4 wd = *reinterpret_cast<const float4*>(wdp + (size_t)(k + kk) * HID);
            float sv0 = (&s0.x)[kk], sv1 = (&s1.x)[kk];
            float pv0 = (&p0.x)[kk], pv1 = (&p1.x)[kk];
            float nv0 = (&n0.x)[kk], nv1 = (&n1.x)[kk];
            #pragma unroll
            for (int c = 0; c < 4; ++c) {
                float wsc = (&ws.x)[c], wdc = (&wd.x)[c];
                aS[0][c] += sv0 * wsc;  aS[1][c] += sv1 * wsc;
                aP[0][c] += pv0 * wdc;  aP[1][c] += pv1 * wdc;
                aN[0][c] += nv0 * wdc;  aN[1][c] += nv1 * wdc;
            }
        }
    }

    float wo[4];
    #pragma unroll
    for (int c = 0; c < 4; ++c) wo[c] = W_out[j4 + c];

    float rP0 = 0.f, rN0 = 0.f, rP1 = 0.f, rN1 = 0.f;
    #pragma unroll
    for (int c = 0; c < 4; ++c) {
        rP0 += fmaxf(aS[0][c] + aP[0][c], 0.f) * wo[c];
        rN0 += fmaxf(aS[0][c] + aN[0][c], 0.f) * wo[c];
        rP1 += fmaxf(aS[1][c] + aP[1][c], 0.f) * wo[c];
        rN1 += fmaxf(aS[1][c] + aN[1][c], 0.f) * wo[c];
    }

    #pragma unroll
    for (int off = 16; off; off >>= 1) {
        rP0 += __shfl_xor(rP0, off);
        rN0 += __shfl_xor(rN0, off);
        rP1 += __shfl_xor(rP1, off);
        rN1 += __shfl_xor(rN1, off);
    }
    if (cg == 0) {
        float bo = b_out[0];
        out[qbase + q0]     = rP0 + bo;
        out[qbase + q1]     = rP1 + bo;
        out[Q + qbase + q0] = rN0 + bo;
        out[Q + qbase + q1] = rN1 + bo;
    }
}

// ---------------- launch ----------------

extern "C" void kernel_launch(void* const* d_in, const int* in_sizes, int n_in,
                              void* d_out, int out_size, void* d_ws, size_t ws_size,
                              hipStream_t stream) {
    const int*   src     = (const int*)d_in[0];
    const int*   dst     = (const int*)d_in[1];
    const float* ef      = (const float*)d_in[2];
    const float* bt      = (const float*)d_in[3];
    const float* node_ts = (const float*)d_in[4];
    const int*   s_idx   = (const int*)d_in[5];
    const int*   p_idx   = (const int*)d_in[6];
    const int*   n_idx   = (const int*)d_in[7];
    const float* time_w  = (const float*)d_in[8];
    const float* time_b  = (const float*)d_in[9];
    const float* W_src   = (const float*)d_in[10];
    const float* b_src   = (const float*)d_in[11];
    const float* W_dst   = (const float*)d_in[12];
    const float* b_dst   = (const float*)d_in[13];
    const float* W_out   = (const float*)d_in[14];
    const float* b_out   = (const float*)d_in[15];
    float*       out     = (float*)d_out;

    // workspace layout (bytes)
    char* ws = (char*)d_ws;
    int*   slot  = (int*)ws;                           // [100000]          @0
    int*   cnt   = (int*)(ws + 512 * 1024);            // [12288]           @512K
    float* tdbuf = (float*)(ws + 1024 * 1024);         // [12288*32] 1.5 MB @1M
    float* h     = (float*)(ws + 3 * 1024 * 1024);     // [12288*256] 12.6MB@3M
    float* efbuf = (float*)(ws + 16 * 1024 * 1024);    // [12288*32*128] 201MB

    k_init<<<(N_NODES / 4 + NSLOT / 4 + 255) / 256, 256, 0, stream>>>(
        (int4*)slot, (int4*)cnt);
    k_claim<<<NSLOT / 256, 256, 0, stream>>>(s_idx, p_idx, n_idx, slot);
    k_build<<<N_EDGES / 256, 256, 0, stream>>>(src, dst, bt, node_ts, ef,
                                               slot, cnt, efbuf, tdbuf);
    k_aggregate<<<NSLOT / 4, 256, 0, stream>>>(cnt, efbuf, tdbuf,
                                               time_w, time_b, h);
    k_predictor<<<Q / QPB, 256, 0, stream>>>(s_idx, p_idx, n_idx, slot, h,
                                             W_src, b_src, W_dst, b_dst,
                                             W_out, b_out, out);
}

// Round 16
// 59.880 us; speedup vs baseline: 1.1181x; 1.1181x over previous
//
#include <hip/hip_runtime.h>

#define N_NODES 100000
#define N_EDGES 320000
#define Q 4096
#define HID 128
#define DIN 256
#define EMB_LD 260      // DIN + 4 pad: q-rows land on distinct bank groups
#define NSLOT (3 * Q)   // 12288
#define CAP 64
#define QPB 8

// ---------------- K1: slot = -1 ----------------
__global__ __launch_bounds__(256) void k_init(int4* __restrict__ slot4) {
    int i = blockIdx.x * 256 + threadIdx.x;
    if (i < N_NODES / 4) slot4[i] = make_int4(-1, -1, -1, -1);
}

// ---------------- K2: claim slots via CAS + zero cnt ----------------
__global__ __launch_bounds__(256) void k_claim(const int* __restrict__ s_idx,
                                               const int* __restrict__ p_idx,
                                               const int* __restrict__ n_idx,
                                               int* __restrict__ slot,
                                               int* __restrict__ cnt) {
    int i = blockIdx.x * 256 + threadIdx.x;   // 0 .. NSLOT-1
    cnt[i] = 0;
    int t = i >> 12;
    int q = i & (Q - 1);
    int node = (t == 0 ? s_idx : (t == 1 ? p_idx : n_idx))[q];
    atomicCAS(&slot[node], -1, i);
}

// ---------------- K3: build per-slot edge lists (int2 = {e, td}) -------
__global__ __launch_bounds__(256) void k_build(
    const int* __restrict__ src, const int* __restrict__ dst,
    const float* __restrict__ bt, const float* __restrict__ node_ts,
    const int* __restrict__ slot, int* __restrict__ cnt,
    int2* __restrict__ edata) {
    int e = blockIdx.x * 256 + threadIdx.x;
    if (e >= N_EDGES) return;
    int sl = slot[dst[e]];
    if (sl < 0) return;
    float td = bt[e] - node_ts[src[e]];
    int pos = atomicAdd(&cnt[sl], 1);
    if (pos < CAP) edata[sl * CAP + pos] = make_int2(e, __float_as_int(td));
}

// ---------------- K4: fused emb-build + predictor ----------------
// 512 blocks x 256 threads (4 waves), 8 queries per block.
// Phase A (gather): wave w owns rows {w, w+4, ..., w+20}; within wave
//   j=lane>>4 is the edge slot (4 edges in flight), g=lane&15 the col group.
// Phase B (GEMM): wave w owns cols [32w,32w+32); lane = (q=lane>>3, g2=lane&7).
__global__ __launch_bounds__(256) void k_fused(
    const int* __restrict__ s_idx, const int* __restrict__ p_idx,
    const int* __restrict__ n_idx, const int* __restrict__ slot,
    const int* __restrict__ cnt, const int2* __restrict__ edata,
    const float* __restrict__ ef,
    const float* __restrict__ time_w, const float* __restrict__ time_b,
    const float* __restrict__ W_src, const float* __restrict__ b_src,
    const float* __restrict__ W_dst, const float* __restrict__ b_dst,
    const float* __restrict__ W_out, const float* __restrict__ b_out,
    float* __restrict__ out) {
    __shared__ float emb[QPB * 3][EMB_LD];   // ~25 KB
    __shared__ float pP[QPB][4], pN[QPB][4];
    const int tid   = threadIdx.x;
    const int qbase = blockIdx.x * QPB;
    const int w     = tid >> 6;
    const int lane  = tid & 63;

    // ---- Phase A: lane-parallel gather ----
    {
        const int j = lane >> 4;          // edge slot 0..3
        const int g = lane & 15;          // col group 0..15
        const float4 tw0 = *reinterpret_cast<const float4*>(time_w + 8 * g);
        const float4 tw1 = *reinterpret_cast<const float4*>(time_w + 8 * g + 4);
        const float4 tb0 = *reinterpret_cast<const float4*>(time_b + 8 * g);
        const float4 tb1 = *reinterpret_cast<const float4*>(time_b + 8 * g + 4);
        for (int row = w; row < QPB * 3; row += 4) {
            int t = row >> 3, q = row & 7;
            const int* ia = (t == 0) ? s_idx : (t == 1) ? p_idx : n_idx;
            int sl = slot[ia[qbase + q]];
            int n = cnt[sl]; if (n > CAP) n = CAP;
            float4 accA = {0.f, 0.f, 0.f, 0.f}, accB = {0.f, 0.f, 0.f, 0.f};
            float4 tcA  = {0.f, 0.f, 0.f, 0.f}, tcB  = {0.f, 0.f, 0.f, 0.f};
            for (int jb = j; jb < n; jb += 4) {
                int2 ed = edata[(size_t)sl * CAP + jb];
                const float* rp = ef + (size_t)ed.x * 128;
                float4 vA = *reinterpret_cast<const float4*>(rp + 4 * g);
                float4 vB = *reinterpret_cast<const float4*>(rp + 64 + 4 * g);
                float td = __int_as_float(ed.y);
                accA.x += vA.x; accA.y += vA.y; accA.z += vA.z; accA.w += vA.w;
                accB.x += vB.x; accB.y += vB.y; accB.z += vB.z; accB.w += vB.w;
                tcA.x += __cosf(td * tw0.x + tb0.x);
                tcA.y += __cosf(td * tw0.y + tb0.y);
                tcA.z += __cosf(td * tw0.z + tb0.z);
                tcA.w += __cosf(td * tw0.w + tb0.w);
                tcB.x += __cosf(td * tw1.x + tb1.x);
                tcB.y += __cosf(td * tw1.y + tb1.y);
                tcB.z += __cosf(td * tw1.z + tb1.z);
                tcB.w += __cosf(td * tw1.w + tb1.w);
            }
            // reduce over edge slots j (lanes g, 16+g, 32+g, 48+g)
#define RED2(v) { v += __shfl_xor(v, 16); v += __shfl_xor(v, 32); }
            RED2(accA.x) RED2(accA.y) RED2(accA.z) RED2(accA.w)
            RED2(accB.x) RED2(accB.y) RED2(accB.z) RED2(accB.w)
            RED2(tcA.x)  RED2(tcA.y)  RED2(tcA.z)  RED2(tcA.w)
            RED2(tcB.x)  RED2(tcB.y)  RED2(tcB.z)  RED2(tcB.w)
#undef RED2
            if (j == 0) {
                *reinterpret_cast<float4*>(&emb[row][4 * g])       = accA;
                *reinterpret_cast<float4*>(&emb[row][64 + 4 * g])  = accB;
                *reinterpret_cast<float4*>(&emb[row][128 + 8 * g]) = tcA;
                *reinterpret_cast<float4*>(&emb[row][132 + 8 * g]) = tcB;
            }
        }
    }
    __syncthreads();

    // ---- Phase B: GEMM + relu + W_out dot ----
    {
        const int q       = lane >> 3;        // 0..7
        const int g2      = lane & 7;         // 0..7
        const int colbase = 32 * w + 4 * g2;  // wave covers 32 cols

        float4 bs = *reinterpret_cast<const float4*>(b_src + colbase);
        float4 bd = *reinterpret_cast<const float4*>(b_dst + colbase);
        float aS[4] = {bs.x, bs.y, bs.z, bs.w};
        float aP[4] = {bd.x, bd.y, bd.z, bd.w};
        float aN[4] = {bd.x, bd.y, bd.z, bd.w};

        const float* e_s = emb[q];
        const float* e_p = emb[QPB + q];
        const float* e_n = emb[2 * QPB + q];

        for (int k = 0; k < DIN; k += 4) {
            float4 sv = *reinterpret_cast<const float4*>(e_s + k);
            float4 pv = *reinterpret_cast<const float4*>(e_p + k);
            float4 nv = *reinterpret_cast<const float4*>(e_n + k);
            #pragma unroll
            for (int kk = 0; kk < 4; ++kk) {
                float4 ws = *reinterpret_cast<const float4*>(W_src + (size_t)(k + kk) * HID + colbase);
                float4 wd = *reinterpret_cast<const float4*>(W_dst + (size_t)(k + kk) * HID + colbase);
                float s1 = (&sv.x)[kk], p1 = (&pv.x)[kk], n1 = (&nv.x)[kk];
                #pragma unroll
                for (int c = 0; c < 4; ++c) {
                    float wsc = (&ws.x)[c], wdc = (&wd.x)[c];
                    aS[c] += s1 * wsc;
                    aP[c] += p1 * wdc;
                    aN[c] += n1 * wdc;
                }
            }
        }

        float4 wo = *reinterpret_cast<const float4*>(W_out + colbase);
        float rP = 0.f, rN = 0.f;
        #pragma unroll
        for (int c = 0; c < 4; ++c) {
            float woc = (&wo.x)[c];
            rP += fmaxf(aS[c] + aP[c], 0.f) * woc;
            rN += fmaxf(aS[c] + aN[c], 0.f) * woc;
        }
        rP += __shfl_xor(rP, 1); rP += __shfl_xor(rP, 2); rP += __shfl_xor(rP, 4);
        rN += __shfl_xor(rN, 1); rN += __shfl_xor(rN, 2); rN += __shfl_xor(rN, 4);
        if (g2 == 0) { pP[q][w] = rP; pN[q][w] = rN; }
    }
    __syncthreads();

    if (tid < QPB) {
        float bo = b_out[0];
        out[qbase + tid]     = pP[tid][0] + pP[tid][1] + pP[tid][2] + pP[tid][3] + bo;
        out[Q + qbase + tid] = pN[tid][0] + pN[tid][1] + pN[tid][2] + pN[tid][3] + bo;
    }
}

// ---------------- launch ----------------

extern "C" void kernel_launch(void* const* d_in, const int* in_sizes, int n_in,
                              void* d_out, int out_size, void* d_ws, size_t ws_size,
                              hipStream_t stream) {
    const int*   src     = (const int*)d_in[0];
    const int*   dst     = (const int*)d_in[1];
    const float* ef      = (const float*)d_in[2];
    const float* bt      = (const float*)d_in[3];
    const float* node_ts = (const float*)d_in[4];
    const int*   s_idx   = (const int*)d_in[5];
    const int*   p_idx   = (const int*)d_in[6];
    const int*   n_idx   = (const int*)d_in[7];
    const float* time_w  = (const float*)d_in[8];
    const float* time_b  = (const float*)d_in[9];
    const float* W_src   = (const float*)d_in[10];
    const float* b_src   = (const float*)d_in[11];
    const float* W_dst   = (const float*)d_in[12];
    const float* b_dst   = (const float*)d_in[13];
    const float* W_out   = (const float*)d_in[14];
    const float* b_out   = (const float*)d_in[15];
    float*       out     = (float*)d_out;

    // workspace layout (bytes)
    char* ws = (char*)d_ws;
    int*   slot  = (int*)ws;                          // [100000]
    int*   cnt   = (int*)(ws + 512 * 1024);           // [12288]
    int2*  edata = (int2*)(ws + 1024 * 1024);         // [12288*64] int2 = 6.3 MB

    k_init<<<(N_NODES / 4 + 255) / 256, 256, 0, stream>>>((int4*)slot);
    k_claim<<<NSLOT / 256, 256, 0, stream>>>(s_idx, p_idx, n_idx, slot, cnt);
    k_build<<<(N_EDGES + 255) / 256, 256, 0, stream>>>(src, dst, bt, node_ts,
                                                       slot, cnt, edata);
    k_fused<<<Q / QPB, 256, 0, stream>>>(s_idx, p_idx, n_idx, slot, cnt,
                                         edata, ef, time_w, time_b,
                                         W_src, b_src, W_dst, b_dst,
                                         W_out, b_out, out);
}

// Round 17
// 50.535 us; speedup vs baseline: 1.3249x; 1.1849x over previous
//
#include <hip/hip_runtime.h>

#define N_NODES 100000
#define N_EDGES 320000
#define Q 4096
#define HID 128
#define DIN 256
#define EMB_LD 260      // DIN + 4 pad: q-rows land on distinct bank groups
#define NSLOT (3 * Q)   // 12288
#define CAP 64
#define QPB 8
#define KT 32           // k-tile staged in LDS

// ---------------- K1: slot = -1 ----------------
__global__ __launch_bounds__(256) void k_init(int4* __restrict__ slot4) {
    int i = blockIdx.x * 256 + threadIdx.x;
    if (i < N_NODES / 4) slot4[i] = make_int4(-1, -1, -1, -1);
}

// ---------------- K2: claim slots via CAS + zero cnt ----------------
__global__ __launch_bounds__(256) void k_claim(const int* __restrict__ s_idx,
                                               const int* __restrict__ p_idx,
                                               const int* __restrict__ n_idx,
                                               int* __restrict__ slot,
                                               int* __restrict__ cnt) {
    int i = blockIdx.x * 256 + threadIdx.x;   // 0 .. NSLOT-1
    cnt[i] = 0;
    int t = i >> 12;
    int q = i & (Q - 1);
    int node = (t == 0 ? s_idx : (t == 1 ? p_idx : n_idx))[q];
    atomicCAS(&slot[node], -1, i);
}

// ---------------- K3: build per-slot edge lists (int2 = {e, td}) -------
__global__ __launch_bounds__(256) void k_build(
    const int* __restrict__ src, const int* __restrict__ dst,
    const float* __restrict__ bt, const float* __restrict__ node_ts,
    const int* __restrict__ slot, int* __restrict__ cnt,
    int2* __restrict__ edata) {
    int e = blockIdx.x * 256 + threadIdx.x;
    if (e >= N_EDGES) return;
    int sl = slot[dst[e]];
    if (sl < 0) return;
    float td = bt[e] - node_ts[src[e]];
    int pos = atomicAdd(&cnt[sl], 1);
    if (pos < CAP) edata[sl * CAP + pos] = make_int2(e, __float_as_int(td));
}

// ---------------- K4: fused emb-build + predictor (LDS-staged W) -------
// 512 blocks x 256 threads (4 waves), 8 queries per block.
// Phase A (gather): wave w owns rows {w, w+4, ..., w+20}; j=lane>>4 edge
//   slot, g=lane&15 col group.
// Phase B (GEMM): W k-tiles staged in LDS once per block; wave w owns cols
//   [32w,32w+32); lane = (q=lane>>3, g2=lane&7); q-groups broadcast-read W.
__global__ __launch_bounds__(256) void k_fused(
    const int* __restrict__ s_idx, const int* __restrict__ p_idx,
    const int* __restrict__ n_idx, const int* __restrict__ slot,
    const int* __restrict__ cnt, const int2* __restrict__ edata,
    const float* __restrict__ ef,
    const float* __restrict__ time_w, const float* __restrict__ time_b,
    const float* __restrict__ W_src, const float* __restrict__ b_src,
    const float* __restrict__ W_dst, const float* __restrict__ b_dst,
    const float* __restrict__ W_out, const float* __restrict__ b_out,
    float* __restrict__ out) {
    __shared__ float emb[QPB * 3][EMB_LD];   // ~25 KB
    __shared__ float wstage[2][KT][HID];     // 32 KB
    __shared__ float pP[QPB][4], pN[QPB][4];
    const int tid   = threadIdx.x;
    const int qbase = blockIdx.x * QPB;
    const int w     = tid >> 6;
    const int lane  = tid & 63;

    // ---- Phase A: lane-parallel gather ----
    {
        const int j = lane >> 4;          // edge slot 0..3
        const int g = lane & 15;          // col group 0..15
        const float4 tw0 = *reinterpret_cast<const float4*>(time_w + 8 * g);
        const float4 tw1 = *reinterpret_cast<const float4*>(time_w + 8 * g + 4);
        const float4 tb0 = *reinterpret_cast<const float4*>(time_b + 8 * g);
        const float4 tb1 = *reinterpret_cast<const float4*>(time_b + 8 * g + 4);
        for (int row = w; row < QPB * 3; row += 4) {
            int t = row >> 3, q = row & 7;
            const int* ia = (t == 0) ? s_idx : (t == 1) ? p_idx : n_idx;
            int sl = slot[ia[qbase + q]];
            int n = cnt[sl]; if (n > CAP) n = CAP;
            float4 accA = {0.f, 0.f, 0.f, 0.f}, accB = {0.f, 0.f, 0.f, 0.f};
            float4 tcA  = {0.f, 0.f, 0.f, 0.f}, tcB  = {0.f, 0.f, 0.f, 0.f};
            for (int jb = j; jb < n; jb += 4) {
                int2 ed = edata[(size_t)sl * CAP + jb];
                const float* rp = ef + (size_t)ed.x * 128;
                float4 vA = *reinterpret_cast<const float4*>(rp + 4 * g);
                float4 vB = *reinterpret_cast<const float4*>(rp + 64 + 4 * g);
                float td = __int_as_float(ed.y);
                accA.x += vA.x; accA.y += vA.y; accA.z += vA.z; accA.w += vA.w;
                accB.x += vB.x; accB.y += vB.y; accB.z += vB.z; accB.w += vB.w;
                tcA.x += __cosf(td * tw0.x + tb0.x);
                tcA.y += __cosf(td * tw0.y + tb0.y);
                tcA.z += __cosf(td * tw0.z + tb0.z);
                tcA.w += __cosf(td * tw0.w + tb0.w);
                tcB.x += __cosf(td * tw1.x + tb1.x);
                tcB.y += __cosf(td * tw1.y + tb1.y);
                tcB.z += __cosf(td * tw1.z + tb1.z);
                tcB.w += __cosf(td * tw1.w + tb1.w);
            }
#define RED2(v) { v += __shfl_xor(v, 16); v += __shfl_xor(v, 32); }
            RED2(accA.x) RED2(accA.y) RED2(accA.z) RED2(accA.w)
            RED2(accB.x) RED2(accB.y) RED2(accB.z) RED2(accB.w)
            RED2(tcA.x)  RED2(tcA.y)  RED2(tcA.z)  RED2(tcA.w)
            RED2(tcB.x)  RED2(tcB.y)  RED2(tcB.z)  RED2(tcB.w)
#undef RED2
            if (j == 0) {
                *reinterpret_cast<float4*>(&emb[row][4 * g])       = accA;
                *reinterpret_cast<float4*>(&emb[row][64 + 4 * g])  = accB;
                *reinterpret_cast<float4*>(&emb[row][128 + 8 * g]) = tcA;
                *reinterpret_cast<float4*>(&emb[row][132 + 8 * g]) = tcB;
            }
        }
    }

    // ---- Phase B: GEMM + relu + W_out dot (W staged per k-tile) ----
    {
        const int q       = lane >> 3;        // 0..7
        const int g2      = lane & 7;         // 0..7
        const int colbase = 32 * w + 4 * g2;  // 0..124

        float4 bs = *reinterpret_cast<const float4*>(b_src + colbase);
        float4 bd = *reinterpret_cast<const float4*>(b_dst + colbase);
        float aS[4] = {bs.x, bs.y, bs.z, bs.w};
        float aP[4] = {bd.x, bd.y, bd.z, bd.w};
        float aN[4] = {bd.x, bd.y, bd.z, bd.w};

        const float* e_s = emb[q];
        const float* e_p = emb[QPB + q];
        const float* e_n = emb[2 * QPB + q];

        for (int kt = 0; kt < DIN; kt += KT) {
            __syncthreads();   // Phase A done (kt=0) / previous tile consumed
            // stage W_src/W_dst[kt:kt+KT][0:128]: 2048 float4, 8 per thread
            for (int r = tid; r < 2 * KT * HID / 4; r += 256) {
                int mat = r >> 10;            // 0..1
                int rem = r & 1023;
                int k   = rem >> 5;           // 0..31
                int c4  = rem & 31;           // 0..31
                const float* Wp = mat ? W_dst : W_src;
                float4 v = *reinterpret_cast<const float4*>(
                    Wp + (size_t)(kt + k) * HID + c4 * 4);
                *reinterpret_cast<float4*>(&wstage[mat][k][c4 * 4]) = v;
            }
            __syncthreads();
            for (int kk = 0; kk < KT; kk += 4) {
                float4 sv = *reinterpret_cast<const float4*>(e_s + kt + kk);
                float4 pv = *reinterpret_cast<const float4*>(e_p + kt + kk);
                float4 nv = *reinterpret_cast<const float4*>(e_n + kt + kk);
                #pragma unroll
                for (int k4 = 0; k4 < 4; ++k4) {
                    float4 ws = *reinterpret_cast<const float4*>(&wstage[0][kk + k4][colbase]);
                    float4 wd = *reinterpret_cast<const float4*>(&wstage[1][kk + k4][colbase]);
                    float s1 = (&sv.x)[k4], p1 = (&pv.x)[k4], n1 = (&nv.x)[k4];
                    #pragma unroll
                    for (int c = 0; c < 4; ++c) {
                        float wsc = (&ws.x)[c], wdc = (&wd.x)[c];
                        aS[c] += s1 * wsc;
                        aP[c] += p1 * wdc;
                        aN[c] += n1 * wdc;
                    }
                }
            }
        }

        float4 wo = *reinterpret_cast<const float4*>(W_out + colbase);
        float rP = 0.f, rN = 0.f;
        #pragma unroll
        for (int c = 0; c < 4; ++c) {
            float woc = (&wo.x)[c];
            rP += fmaxf(aS[c] + aP[c], 0.f) * woc;
            rN += fmaxf(aS[c] + aN[c], 0.f) * woc;
        }
        rP += __shfl_xor(rP, 1); rP += __shfl_xor(rP, 2); rP += __shfl_xor(rP, 4);
        rN += __shfl_xor(rN, 1); rN += __shfl_xor(rN, 2); rN += __shfl_xor(rN, 4);
        if (g2 == 0) { pP[q][w] = rP; pN[q][w] = rN; }
    }
    __syncthreads();

    if (tid < QPB) {
        float bo = b_out[0];
        out[qbase + tid]     = pP[tid][0] + pP[tid][1] + pP[tid][2] + pP[tid][3] + bo;
        out[Q + qbase + tid] = pN[tid][0] + pN[tid][1] + pN[tid][2] + pN[tid][3] + bo;
    }
}

// ---------------- launch ----------------

extern "C" void kernel_launch(void* const* d_in, const int* in_sizes, int n_in,
                              void* d_out, int out_size, void* d_ws, size_t ws_size,
                              hipStream_t stream) {
    const int*   src     = (const int*)d_in[0];
    const int*   dst     = (const int*)d_in[1];
    const float* ef      = (const float*)d_in[2];
    const float* bt      = (const float*)d_in[3];
    const float* node_ts = (const float*)d_in[4];
    const int*   s_idx   = (const int*)d_in[5];
    const int*   p_idx   = (const int*)d_in[6];
    const int*   n_idx   = (const int*)d_in[7];
    const float* time_w  = (const float*)d_in[8];
    const float* time_b  = (const float*)d_in[9];
    const float* W_src   = (const float*)d_in[10];
    const float* b_src   = (const float*)d_in[11];
    const float* W_dst   = (const float*)d_in[12];
    const float* b_dst   = (const float*)d_in[13];
    const float* W_out   = (const float*)d_in[14];
    const float* b_out   = (const float*)d_in[15];
    float*       out     = (float*)d_out;

    // workspace layout (bytes)
    char* ws = (char*)d_ws;
    int*   slot  = (int*)ws;                          // [100000]
    int*   cnt   = (int*)(ws + 512 * 1024);           // [12288]
    int2*  edata = (int2*)(ws + 1024 * 1024);         // [12288*64] int2 = 6.3 MB

    k_init<<<(N_NODES / 4 + 255) / 256, 256, 0, stream>>>((int4*)slot);
    k_claim<<<NSLOT / 256, 256, 0, stream>>>(s_idx, p_idx, n_idx, slot, cnt);
    k_build<<<(N_EDGES + 255) / 256, 256, 0, stream>>>(src, dst, bt, node_ts,
                                                       slot, cnt, edata);
    k_fused<<<Q / QPB, 256, 0, stream>>>(s_idx, p_idx, n_idx, slot, cnt,
                                         edata, ef, time_w, time_b,
                                         W_src, b_src, W_dst, b_dst,
                                         W_out, b_out, out);
}

// Round 18
// 49.622 us; speedup vs baseline: 1.3493x; 1.0184x over previous
//
#include <hip/hip_runtime.h>

#define N_NODES 100000
#define N_EDGES 320000
#define Q 4096
#define HID 128
#define DIN 256
#define EMB_LD 260      // DIN + 4 pad: q-rows land on distinct bank groups
#define NSLOT (3 * Q)   // 12288
#define CAP 64
#define QPB 8
#define KT 32           // k-tile staged in LDS

// ---------------- K1: slot = -1 ----------------
__global__ __launch_bounds__(256) void k_init(int4* __restrict__ slot4) {
    int i = blockIdx.x * 256 + threadIdx.x;
    if (i < N_NODES / 4) slot4[i] = make_int4(-1, -1, -1, -1);
}

// ---------------- K2: claim slots via CAS + zero cnt ----------------
__global__ __launch_bounds__(256) void k_claim(const int* __restrict__ s_idx,
                                               const int* __restrict__ p_idx,
                                               const int* __restrict__ n_idx,
                                               int* __restrict__ slot,
                                               int* __restrict__ cnt) {
    int i = blockIdx.x * 256 + threadIdx.x;   // 0 .. NSLOT-1
    cnt[i] = 0;
    int t = i >> 12;
    int q = i & (Q - 1);
    int node = (t == 0 ? s_idx : (t == 1 ? p_idx : n_idx))[q];
    atomicCAS(&slot[node], -1, i);
}

// ---------------- K3: build per-slot edge lists (int2 = {e, td}) -------
__global__ __launch_bounds__(256) void k_build(
    const int* __restrict__ src, const int* __restrict__ dst,
    const float* __restrict__ bt, const float* __restrict__ node_ts,
    const int* __restrict__ slot, int* __restrict__ cnt,
    int2* __restrict__ edata) {
    int e = blockIdx.x * 256 + threadIdx.x;
    if (e >= N_EDGES) return;
    int sl = slot[dst[e]];
    if (sl < 0) return;
    float td = bt[e] - node_ts[src[e]];
    int pos = atomicAdd(&cnt[sl], 1);
    if (pos < CAP) edata[sl * CAP + pos] = make_int2(e, __float_as_int(td));
}

// ---------------- K4: fused emb-build + predictor ----------------
// 512 blocks x 256 threads (4 waves), 8 queries per block.
// Phase A (gather): wave w owns rows {w, w+4, ..., w+20}; j=lane>>4 edge
//   slot, g=lane&15 col group.
// Phase B (GEMM): W k-tiles staged in LDS; thread = 2 queries (qp, qp+4)
//   x 4 cols x 3 mats; the two 128-thread halves split each k-tile.
__global__ __launch_bounds__(256) void k_fused(
    const int* __restrict__ s_idx, const int* __restrict__ p_idx,
    const int* __restrict__ n_idx, const int* __restrict__ slot,
    const int* __restrict__ cnt, const int2* __restrict__ edata,
    const float* __restrict__ ef,
    const float* __restrict__ time_w, const float* __restrict__ time_b,
    const float* __restrict__ W_src, const float* __restrict__ b_src,
    const float* __restrict__ W_dst, const float* __restrict__ b_dst,
    const float* __restrict__ W_out, const float* __restrict__ b_out,
    float* __restrict__ out) {
    __shared__ float emb[QPB * 3][EMB_LD];   // ~25 KB (re-used as partials)
    __shared__ float wstage[2][KT][HID];     // 32 KB
    const int tid   = threadIdx.x;
    const int qbase = blockIdx.x * QPB;
    const int w     = tid >> 6;
    const int lane  = tid & 63;

    // ---- Phase A: lane-parallel gather ----
    {
        const int j = lane >> 4;          // edge slot 0..3
        const int g = lane & 15;          // col group 0..15
        const float4 tw0 = *reinterpret_cast<const float4*>(time_w + 8 * g);
        const float4 tw1 = *reinterpret_cast<const float4*>(time_w + 8 * g + 4);
        const float4 tb0 = *reinterpret_cast<const float4*>(time_b + 8 * g);
        const float4 tb1 = *reinterpret_cast<const float4*>(time_b + 8 * g + 4);
        for (int row = w; row < QPB * 3; row += 4) {
            int t = row >> 3, q = row & 7;
            const int* ia = (t == 0) ? s_idx : (t == 1) ? p_idx : n_idx;
            int sl = slot[ia[qbase + q]];
            int n = cnt[sl]; if (n > CAP) n = CAP;
            float4 accA = {0.f, 0.f, 0.f, 0.f}, accB = {0.f, 0.f, 0.f, 0.f};
            float4 tcA  = {0.f, 0.f, 0.f, 0.f}, tcB  = {0.f, 0.f, 0.f, 0.f};
            for (int jb = j; jb < n; jb += 4) {
                int2 ed = edata[(size_t)sl * CAP + jb];
                const float* rp = ef + (size_t)ed.x * 128;
                float4 vA = *reinterpret_cast<const float4*>(rp + 4 * g);
                float4 vB = *reinterpret_cast<const float4*>(rp + 64 + 4 * g);
                float td = __int_as_float(ed.y);
                accA.x += vA.x; accA.y += vA.y; accA.z += vA.z; accA.w += vA.w;
                accB.x += vB.x; accB.y += vB.y; accB.z += vB.z; accB.w += vB.w;
                tcA.x += __cosf(td * tw0.x + tb0.x);
                tcA.y += __cosf(td * tw0.y + tb0.y);
                tcA.z += __cosf(td * tw0.z + tb0.z);
                tcA.w += __cosf(td * tw0.w + tb0.w);
                tcB.x += __cosf(td * tw1.x + tb1.x);
                tcB.y += __cosf(td * tw1.y + tb1.y);
                tcB.z += __cosf(td * tw1.z + tb1.z);
                tcB.w += __cosf(td * tw1.w + tb1.w);
            }
#define RED2(v) { v += __shfl_xor(v, 16); v += __shfl_xor(v, 32); }
            RED2(accA.x) RED2(accA.y) RED2(accA.z) RED2(accA.w)
            RED2(accB.x) RED2(accB.y) RED2(accB.z) RED2(accB.w)
            RED2(tcA.x)  RED2(tcA.y)  RED2(tcA.z)  RED2(tcA.w)
            RED2(tcB.x)  RED2(tcB.y)  RED2(tcB.z)  RED2(tcB.w)
#undef RED2
            if (j == 0) {
                *reinterpret_cast<float4*>(&emb[row][4 * g])       = accA;
                *reinterpret_cast<float4*>(&emb[row][64 + 4 * g])  = accB;
                *reinterpret_cast<float4*>(&emb[row][128 + 8 * g]) = tcA;
                *reinterpret_cast<float4*>(&emb[row][132 + 8 * g]) = tcB;
            }
        }
    }

    // ---- Phase B: GEMM, thread = 2 queries x 4 cols; halves split k ----
    const int half    = tid >> 7;         // 0,1
    const int hid     = tid & 127;
    const int qp      = hid >> 5;         // 0..3 -> queries qp, qp+4
    const int g2      = hid & 31;         // 0..31
    const int colbase = g2 << 2;          // 0..124

    float aS0[4], aS1[4], aP0[4], aP1[4], aN0[4], aN1[4];
    {
        float4 bs = *reinterpret_cast<const float4*>(b_src + colbase);
        float4 bd = *reinterpret_cast<const float4*>(b_dst + colbase);
        #pragma unroll
        for (int c = 0; c < 4; ++c) {
            float bsc = half ? 0.f : (&bs.x)[c];
            float bdc = half ? 0.f : (&bd.x)[c];
            aS0[c] = bsc; aS1[c] = bsc;
            aP0[c] = bdc; aP1[c] = bdc;
            aN0[c] = bdc; aN1[c] = bdc;
        }
    }

    const float* e_s0 = emb[qp];
    const float* e_s1 = emb[qp + 4];
    const float* e_p0 = emb[QPB + qp];
    const float* e_p1 = emb[QPB + qp + 4];
    const float* e_n0 = emb[2 * QPB + qp];
    const float* e_n1 = emb[2 * QPB + qp + 4];

    for (int kt = 0; kt < DIN; kt += KT) {
        __syncthreads();   // Phase A done (kt=0) / previous tile consumed
        // stage W_src/W_dst[kt:kt+KT][0:128]: 2048 float4, 8 per thread
        for (int r = tid; r < 2 * KT * HID / 4; r += 256) {
            int mat = r >> 10;            // 0..1
            int rem = r & 1023;
            int k   = rem >> 5;           // 0..31
            int c4  = rem & 31;           // 0..31
            const float* Wp = mat ? W_dst : W_src;
            float4 v = *reinterpret_cast<const float4*>(
                Wp + (size_t)(kt + k) * HID + c4 * 4);
            *reinterpret_cast<float4*>(&wstage[mat][k][c4 * 4]) = v;
        }
        __syncthreads();
        const int lk0 = half * (KT / 2);          // 0 or 16
        const int kb  = kt + lk0;
        for (int kk = 0; kk < KT / 2; kk += 4) {
            float4 s0 = *reinterpret_cast<const float4*>(e_s0 + kb + kk);
            float4 s1 = *reinterpret_cast<const float4*>(e_s1 + kb + kk);
            float4 p0 = *reinterpret_cast<const float4*>(e_p0 + kb + kk);
            float4 p1 = *reinterpret_cast<const float4*>(e_p1 + kb + kk);
            float4 n0 = *reinterpret_cast<const float4*>(e_n0 + kb + kk);
            float4 n1 = *reinterpret_cast<const float4*>(e_n1 + kb + kk);
            #pragma unroll
            for (int k4 = 0; k4 < 4; ++k4) {
                float4 ws = *reinterpret_cast<const float4*>(&wstage[0][lk0 + kk + k4][colbase]);
                float4 wd = *reinterpret_cast<const float4*>(&wstage[1][lk0 + kk + k4][colbase]);
                float sv0 = (&s0.x)[k4], sv1 = (&s1.x)[k4];
                float pv0 = (&p0.x)[k4], pv1 = (&p1.x)[k4];
                float nv0 = (&n0.x)[k4], nv1 = (&n1.x)[k4];
                #pragma unroll
                for (int c = 0; c < 4; ++c) {
                    float wsc = (&ws.x)[c], wdc = (&wd.x)[c];
                    aS0[c] += sv0 * wsc;  aS1[c] += sv1 * wsc;
                    aP0[c] += pv0 * wdc;  aP1[c] += pv1 * wdc;
                    aN0[c] += nv0 * wdc;  aN1[c] += nv1 * wdc;
                }
            }
        }
    }

    // ---- merge halves via LDS overlay on emb, then relu + W_out dot ----
    float (*part)[24] = reinterpret_cast<float(*)[24]>(&emb[0][0]);  // 128x24
    __syncthreads();                      // all emb reads done
    if (half) {
        float* p = part[hid];
        #pragma unroll
        for (int c = 0; c < 4; ++c) {
            p[c]      = aS0[c]; p[4 + c]  = aS1[c];
            p[8 + c]  = aP0[c]; p[12 + c] = aP1[c];
            p[16 + c] = aN0[c]; p[20 + c] = aN1[c];
        }
    }
    __syncthreads();
    if (!half) {
        const float* p = part[hid];
        float4 wo = *reinterpret_cast<const float4*>(W_out + colbase);
        float rP0 = 0.f, rN0 = 0.f, rP1 = 0.f, rN1 = 0.f;
        #pragma unroll
        for (int c = 0; c < 4; ++c) {
            float sc0 = aS0[c] + p[c],      sc1 = aS1[c] + p[4 + c];
            float pc0 = aP0[c] + p[8 + c],  pc1 = aP1[c] + p[12 + c];
            float nc0 = aN0[c] + p[16 + c], nc1 = aN1[c] + p[20 + c];
            float woc = (&wo.x)[c];
            rP0 += fmaxf(sc0 + pc0, 0.f) * woc;
            rN0 += fmaxf(sc0 + nc0, 0.f) * woc;
            rP1 += fmaxf(sc1 + pc1, 0.f) * woc;
            rN1 += fmaxf(sc1 + nc1, 0.f) * woc;
        }
        #pragma unroll
        for (int off = 1; off < 32; off <<= 1) {
            rP0 += __shfl_xor(rP0, off);
            rN0 += __shfl_xor(rN0, off);
            rP1 += __shfl_xor(rP1, off);
            rN1 += __shfl_xor(rN1, off);
        }
        if (g2 == 0) {
            float bo = b_out[0];
            out[qbase + qp]         = rP0 + bo;
            out[Q + qbase + qp]     = rN0 + bo;
            out[qbase + qp + 4]     = rP1 + bo;
            out[Q + qbase + qp + 4] = rN1 + bo;
        }
    }
}

// ---------------- launch ----------------

extern "C" void kernel_launch(void* const* d_in, const int* in_sizes, int n_in,
                              void* d_out, int out_size, void* d_ws, size_t ws_size,
                              hipStream_t stream) {
    const int*   src     = (const int*)d_in[0];
    const int*   dst     = (const int*)d_in[1];
    const float* ef      = (const float*)d_in[2];
    const float* bt      = (const float*)d_in[3];
    const float* node_ts = (const float*)d_in[4];
    const int*   s_idx   = (const int*)d_in[5];
    const int*   p_idx   = (const int*)d_in[6];
    const int*   n_idx   = (const int*)d_in[7];
    const float* time_w  = (const float*)d_in[8];
    const float* time_b  = (const float*)d_in[9];
    const float* W_src   = (const float*)d_in[10];
    const float* b_src   = (const float*)d_in[11];
    const float* W_dst   = (const float*)d_in[12];
    const float* b_dst   = (const float*)d_in[13];
    const float* W_out   = (const float*)d_in[14];
    const float* b_out   = (const float*)d_in[15];
    float*       out     = (float*)d_out;

    // workspace layout (bytes)
    char* ws = (char*)d_ws;
    int*   slot  = (int*)ws;                          // [100000]
    int*   cnt   = (int*)(ws + 512 * 1024);           // [12288]
    int2*  edata = (int2*)(ws + 1024 * 1024);         // [12288*64] int2 = 6.3 MB

    k_init<<<(N_NODES / 4 + 255) / 256, 256, 0, stream>>>((int4*)slot);
    k_claim<<<NSLOT / 256, 256, 0, stream>>>(s_idx, p_idx, n_idx, slot, cnt);
    k_build<<<(N_EDGES + 255) / 256, 256, 0, stream>>>(src, dst, bt, node_ts,
                                                       slot, cnt, edata);
    k_fused<<<Q / QPB, 256, 0, stream>>>(s_idx, p_idx, n_idx, slot, cnt,
                                         edata, ef, time_w, time_b,
                                         W_src, b_src, W_dst, b_dst,
                                         W_out, b_out, out);
}